// Round 15
// baseline (124.761 us; speedup 1.0000x reference)
//
#include <hip/hip_runtime.h>

#define NROWS 32768
#define NE    1024
#define ED    64
#define RPW   8                // rows per wave
#define NW    4                // waves per block
#define RPB   (RPW * NW)       // 32 rows per block

typedef float4 f4;

// ---------------------------------------------------------------------------
// Prep: eTi[k4][code] = f4(cb[code][4k4..4k4+3]) (k4-blocked transpose,
// coalesced writes) + ssq[code] with numpy pairwise-8 op order.
// ---------------------------------------------------------------------------
__global__ void vq_prep(const float* __restrict__ cb, f4* __restrict__ eTi,
                        float* __restrict__ ssq)
{
    int j = blockIdx.x * blockDim.x + threadIdx.x;   // 0..1023 code id
    const f4* crow = (const f4*)(cb + (size_t)j * ED);
    f4 v[16];
#pragma unroll
    for (int i = 0; i < 16; ++i) v[i] = crow[i];
    {
#pragma clang fp contract(off)
        float r0 = v[0].x*v[0].x, r1 = v[0].y*v[0].y;
        float r2 = v[0].z*v[0].z, r3 = v[0].w*v[0].w;
        float r4 = v[1].x*v[1].x, r5 = v[1].y*v[1].y;
        float r6 = v[1].z*v[1].z, r7 = v[1].w*v[1].w;
#pragma unroll
        for (int q = 2; q < 16; q += 2) {
            r0 += v[q].x*v[q].x;     r1 += v[q].y*v[q].y;
            r2 += v[q].z*v[q].z;     r3 += v[q].w*v[q].w;
            r4 += v[q+1].x*v[q+1].x; r5 += v[q+1].y*v[q+1].y;
            r6 += v[q+1].z*v[q+1].z; r7 += v[q+1].w*v[q+1].w;
        }
        ssq[j] = ((r0+r1)+(r2+r3)) + ((r4+r5)+(r6+r7));
    }
#pragma unroll
    for (int k4 = 0; k4 < 16; ++k4) eTi[(size_t)k4 * NE + j] = v[k4];
}

// ---------------------------------------------------------------------------
// Main: counters SPLIT cleanly, no LDS staging, no barriers in the scan:
//   e: per-lane coalesced global_load_dwordx4 from eTi (vmcnt, in-order ->
//      compiler software-pipelines across k4 with unroll 4)
//   z: wave-uniform s_load_dwordx4, r7-proven (lgkmcnt = SMEM only)
//  - 1024 blocks x 256 thr; wave = 8 disjoint rows, scans ALL 1024 codes
//    (no z duplication); no launch_bounds min-waves (clamp-spill lesson).
// Numerics identical per (row,code) to passing r7/r10: cn/ssq numpy
// pairwise-8; dot ascending-k single-acc fmaf; d = fl(fl(cn+ssq)-2*acc);
// first-index argmin (ascending g per lane, lex (d,idx) butterfly).
// ---------------------------------------------------------------------------
__global__ __launch_bounds__(256)
void vq_main(const float* __restrict__ z, const float* __restrict__ cb,
             const f4* __restrict__ eTi, const float* __restrict__ ssq,
             float* __restrict__ out, float* __restrict__ partials)
{
    __shared__ int   idxsh[RPB];
    __shared__ float wsum[NW];

    const int tid  = threadIdx.x;
    const int lane = tid & 63;
    const int w    = tid >> 6;                               // wave 0..3
    const int w_u  = __builtin_amdgcn_readfirstlane(w);      // scalar wave id
    const int rowbase = blockIdx.x * RPB;

    const float* zw = z + (size_t)(rowbase + w_u * RPW) * ED; // scalar base

    // ---- row norms for this wave's 8 rows, numpy pairwise-8 ----
    float cn[RPW];
    {
        const int rl = lane >> 3;            // row within wave's 8
        const int jj = lane & 7;             // accumulator index
        const float* zr = zw + (size_t)rl * ED;
        float a;
        {
#pragma clang fp contract(off)
            a = 0.f;
#pragma unroll
            for (int i = 0; i < 8; ++i) { float v = zr[8*i + jj]; a += v*v; }
        }
        a += __shfl_xor(a, 1);
        a += __shfl_xor(a, 2);
        a += __shfl_xor(a, 4);
#pragma unroll
        for (int r = 0; r < RPW; ++r) cn[r] = __shfl(a, r * 8);
    }

    float bestv[RPW];
    int   besti[RPW];
#pragma unroll
    for (int r = 0; r < RPW; ++r) { bestv[r] = INFINITY; besti[r] = 0; }

    // ---- scan all 1024 codes in 16 groups of 64 (code = g*64 + lane) ----
    for (int g = 0; g < 16; ++g) {
        const int c = g * 64 + lane;                 // this lane's code
        const float sq = ssq[c];                     // coalesced, L2-hot

        float acc[RPW];
#pragma unroll
        for (int r = 0; r < RPW; ++r) acc[r] = 0.f;

#pragma unroll 4
        for (int k4 = 0; k4 < 16; ++k4) {
            f4 e  = eTi[(size_t)k4 * NE + c];        // global dwordx4 (vmcnt)
            f4 z0 = *(const f4*)(zw + 0*ED + 4*k4);  // s_load_dwordx4 (SMEM)
            f4 z1 = *(const f4*)(zw + 1*ED + 4*k4);
            f4 z2 = *(const f4*)(zw + 2*ED + 4*k4);
            f4 z3 = *(const f4*)(zw + 3*ED + 4*k4);
            f4 z4 = *(const f4*)(zw + 4*ED + 4*k4);
            f4 z5 = *(const f4*)(zw + 5*ED + 4*k4);
            f4 z6 = *(const f4*)(zw + 6*ED + 4*k4);
            f4 z7 = *(const f4*)(zw + 7*ED + 4*k4);
#define ROWFMA(r, zz)                                 \
            acc[r] = fmaf(e.x, zz.x, acc[r]);         \
            acc[r] = fmaf(e.y, zz.y, acc[r]);         \
            acc[r] = fmaf(e.z, zz.z, acc[r]);         \
            acc[r] = fmaf(e.w, zz.w, acc[r]);
            ROWFMA(0, z0) ROWFMA(1, z1) ROWFMA(2, z2) ROWFMA(3, z3)
            ROWFMA(4, z4) ROWFMA(5, z5) ROWFMA(6, z6) ROWFMA(7, z7)
#undef ROWFMA
        }

        {
#pragma clang fp contract(off)
#pragma unroll
            for (int r = 0; r < RPW; ++r) {
                float t1 = cn[r] + sq;
                float d  = t1 - 2.0f * acc[r];       // 2*acc exact
                if (d < bestv[r]) { bestv[r] = d; besti[r] = c; }
            }
        }
    }

    // ---- cross-lane lexicographic (val, idx) argmin + epilogue ----
    float lp = 0.f;
#pragma unroll
    for (int r = 0; r < RPW; ++r) {
        float v = bestv[r];
        int   i = besti[r];
#pragma unroll
        for (int m = 1; m < 64; m <<= 1) {
            float ov = __shfl_xor(v, m);
            int   oi = __shfl_xor(i, m);
            if (ov < v || (ov == v && oi < i)) { v = ov; i = oi; }
        }
        i &= (NE - 1);                       // defensive no-op
        const int grow = rowbase + w * RPW + r;
        float zq, zz, diff, st;
        {
#pragma clang fp contract(off)
            zq   = cb[(size_t)i * ED + lane];
            zz   = z [(size_t)grow * ED + lane];
            diff = zq - zz;                  // (z_q - z)
            st   = zz + diff;                // z + sg(z_q - z)
            lp  += diff * diff;
        }
        out[(size_t)grow * ED + lane] = st;
        if (lane == 0) idxsh[w * RPW + r] = i;
    }

    // ---- deterministic loss partial ----
#pragma unroll
    for (int m = 1; m < 64; m <<= 1) lp += __shfl_xor(lp, m);
    if (lane == 0) wsum[w] = lp;
    __syncthreads();

    // ---- uniform coalesced idx store (f32) ----
    if (tid < RPB) {
        int iv = idxsh[tid] & (NE - 1);
        out[(size_t)NROWS * ED + rowbase + tid] = (float)iv;
    }
    if (tid == 0)
        partials[blockIdx.x] = (wsum[0] + wsum[1]) + (wsum[2] + wsum[3]);
}

// ---------------------------------------------------------------------------
// Finalize: deterministic tree-sum of 1024 partials -> loss scalar (f32)
// ---------------------------------------------------------------------------
__global__ void vq_finalize(const float* __restrict__ partials,
                            float* __restrict__ out)
{
    __shared__ float red[256];
    int t = threadIdx.x;
    float s = (partials[t] + partials[t + 256]) + (partials[t + 512] + partials[t + 768]);
    red[t] = s;
    __syncthreads();
    for (int m = 128; m > 0; m >>= 1) {
        if (t < m) red[t] += red[t + m];
        __syncthreads();
    }
    if (t == 0) {
        float mean = red[0] / (float)((size_t)NROWS * ED);
        out[(size_t)NROWS * ED + NROWS] = mean + 0.25f * mean;  // (1+BETA)*mean
    }
}

extern "C" void kernel_launch(void* const* d_in, const int* in_sizes, int n_in,
                              void* d_out, int out_size, void* d_ws, size_t ws_size,
                              hipStream_t stream)
{
    (void)in_sizes; (void)n_in; (void)out_size; (void)ws_size;
    const float* z  = (const float*)d_in[0];
    const float* cb = (const float*)d_in[1];
    float* out = (float*)d_out;

    f4*    eTi      = (f4*)d_ws;                     // 16*1024 f4 = 256 KB
    float* ssq      = (float*)(eTi + 16 * NE);       // 1024 f32
    float* partials = ssq + NE;                      // 1024 f32

    vq_prep<<<4, 256, 0, stream>>>(cb, eTi, ssq);
    vq_main<<<1024, 256, 0, stream>>>(z, cb, eTi, ssq, out, partials);
    vq_finalize<<<1, 256, 0, stream>>>(partials, out);
}